// Round 13
// baseline (14624.854 us; speedup 1.0000x reference)
//
#include <hip/hip_runtime.h>

#define BB 32
#define TT 2048
#define HH 256
#define NT 512

typedef unsigned long long ull;
typedef unsigned int uint;

__device__ __forceinline__ float sigm(float v) { return 1.0f / (1.0f + __expf(-v)); }

__device__ __forceinline__ int aload(const int* p) {
  return __hip_atomic_load(p, __ATOMIC_RELAXED, __HIP_MEMORY_SCOPE_AGENT);
}
__device__ __forceinline__ void astore(int* p, int v) {
  __hip_atomic_store(p, v, __ATOMIC_RELAXED, __HIP_MEMORY_SCOPE_AGENT);
}
__device__ __forceinline__ ull aload64(const ull* p) {
  return __hip_atomic_load(p, __ATOMIC_RELAXED, __HIP_MEMORY_SCOPE_AGENT);
}
__device__ __forceinline__ void astore64(ull* p, ull v) {
  __hip_atomic_store(p, v, __ATOMIC_RELAXED, __HIP_MEMORY_SCOPE_AGENT);
}

// Grid 512, 2 WGs/CU anti-phase (layer 0 + layer 1 of the same batch group share a CU).
// Communities: (layer, grp) = 16 total, grp = bid&7 (XCD-aligned), 32 WGs each, 4 batches.
// Ring: per community 2 slots x 1024 pairs {tag(lo32), hbits(hi32)}, idx = bl*256+col.
// Per-thread tile: 2 gates (pair gh) x 2 batches x K-slice 32 (k = j*64 + ks*4, 16 ks
// lanes) -> weights 16 float4 = 64 VGPR, 8 FMA per ds_read_b128 (2x round-12 ratio).
// Reduction: butterfly xor{1,2,4,8} over ks, then xor16 exchange across gate-pair bit.
__global__ __launch_bounds__(NT) void lstm_scan(
    const float* __restrict__ x,     // [B,T,H]
    const float* __restrict__ W,     // [L,4,H,2H]
    const float* __restrict__ bias,  // [L,4,H]
    float* __restrict__ out,         // [B,T,H] + hT[B,H] + cT[B,H]
    ull* __restrict__ ring,
    int* __restrict__ sync)
{
    const int bid   = blockIdx.x;
    const int grp   = bid & 7;        // batch group (4 batches) == XCD slot
    const int layer = (bid >> 3) & 1;
    const int ug    = bid >> 4;       // 0..31
    const int c     = layer * 8 + grp;
    const int tid   = threadIdx.x;
    const int lane  = tid & 63;
    const int wave  = tid >> 6;       // col within group
    const int ks    = lane & 15;      // K-slice lane (bits 0-3)
    const int gh    = (lane >> 4) & 1;// gate pair: 0 -> {i,f}, 1 -> {o,chat}
    const int bh    = lane >> 5;      // batch half
    const int col   = ug * 8 + wave;
    const int rb    = bh * 2;         // local batch base (2 rows/thread)

    int* mOwn = sync + c * 32;
    int* mSib = sync + (8 + grp) * 32;             // layer-1 community, same grp
    ull* ringOwn = ring + (size_t)c * 2048;        // 2 slots x 1024
    ull* ringIn  = ring + (size_t)grp * 2048;      // layer-0 community, same grp

    __shared__ float inp[4][268];
    __shared__ float hrec[4][268];

    // weight-stationary: wA/wB[j] = W[l][gh*2 / gh*2+1][col][j*64 + ks*4 .. +3]
    float4 wA[8], wB[8];
    const float* WA = W + (((size_t)layer * 4 + gh * 2)     * HH + col) * (2 * HH);
    const float* WBp = W + (((size_t)layer * 4 + gh * 2 + 1) * HH + col) * (2 * HH);
    #pragma unroll
    for (int j = 0; j < 8; ++j) {
        wA[j] = *(const float4*)(WA  + j * 64 + ks * 4);
        wB[j] = *(const float4*)(WBp + j * 64 + ks * 4);
    }

    float bb[4];
    #pragma unroll
    for (int g = 0; g < 4; ++g) bb[g] = bias[((size_t)layer * 4 + g) * HH + col];

    const int prow  = tid >> 7;          // staging row (local batch 0..3)
    const int pcol2 = (tid & 127) << 1;  // staging col base (2 pairs/thread)

    float c_state = 0.f;  // valid on publish lanes (gh==0 && ks<2): bl = rb+ks

    for (int t = 0; t < TT; ++t) {
        // ---- (1) input stage: x (layer0) or h0 ring poll (layer1) ----
        if (layer == 0) {
            *(float2*)&inp[prow][pcol2] =
                *(const float2*)(x + ((size_t)(grp * 4 + prow) * TT + t) * HH + pcol2);
        } else {
            const ull* rin = ringIn + (t & 1) * 1024 + 2 * tid;  // h0(t), tag t+1
            const uint want = (uint)(t + 1);
            uint pend = 0x3u; ull v[2];
            for (;;) {
                #pragma unroll
                for (int j = 0; j < 2; ++j)
                    if (pend & (1u << j)) v[j] = aload64(&rin[j]);
                #pragma unroll
                for (int j = 0; j < 2; ++j)
                    if ((pend & (1u << j)) && (uint)v[j] == want) {
                        inp[prow][pcol2 + j] = __uint_as_float((uint)(v[j] >> 32));
                        pend &= ~(1u << j);
                    }
                if (!pend) break;
                __builtin_amdgcn_s_sleep(1);
            }
        }
        __syncthreads();  // inp ready

        // ---- (2) recurrent poll -> hrec (2 pairs/thread) ----
        {
            const ull* rr_ = ringOwn + ((t + 1) & 1) * 1024 + 2 * tid;  // h_l(t-1), tag t
            const uint want = (uint)t;
            uint pend = 0x3u; ull v[2];
            for (;;) {
                #pragma unroll
                for (int j = 0; j < 2; ++j)
                    if (pend & (1u << j)) v[j] = aload64(&rr_[j]);
                #pragma unroll
                for (int j = 0; j < 2; ++j)
                    if ((pend & (1u << j)) && (uint)v[j] == want) {
                        hrec[prow][pcol2 + j] = __uint_as_float((uint)(v[j] >> 32));
                        pend &= ~(1u << j);
                    }
                if (!pend) break;
                __builtin_amdgcn_s_sleep(1);
            }
        }
        // ---- (3) WAR gates (overlap stragglers) ----
        if (tid < 32)                    { while (aload(&mOwn[tid]) < t)          __builtin_amdgcn_s_sleep(1); }
        else if (layer == 0 && tid < 64) { while (aload(&mSib[tid - 32]) < t - 1) __builtin_amdgcn_s_sleep(1); }
        __syncthreads();  // hrec ready + gates passed
        if (tid == 0) astore(&mOwn[ug], t + 1);  // staged step t (inp + hrec consumed)

        // ---- (4) dot: 2 reads feed 16 FMA per j (2 rows x 2 gates x 4k) ----
        float a00 = 0.f, a01 = 0.f, a10 = 0.f, a11 = 0.f;
        #pragma unroll
        for (int j = 0; j < 4; ++j) {
            const int kof = j * 64 + ks * 4;
            float4 w0 = wA[j], w1 = wB[j];
            float4 v0 = *(const float4*)&inp[rb + 0][kof];
            float4 v1 = *(const float4*)&inp[rb + 1][kof];
            a00 += v0.x * w0.x + v0.y * w0.y + v0.z * w0.z + v0.w * w0.w;
            a01 += v0.x * w1.x + v0.y * w1.y + v0.z * w1.z + v0.w * w1.w;
            a10 += v1.x * w0.x + v1.y * w0.y + v1.z * w0.z + v1.w * w0.w;
            a11 += v1.x * w1.x + v1.y * w1.y + v1.z * w1.z + v1.w * w1.w;
        }
        #pragma unroll
        for (int j = 4; j < 8; ++j) {
            const int kof = (j - 4) * 64 + ks * 4;
            float4 w0 = wA[j], w1 = wB[j];
            float4 v0 = *(const float4*)&hrec[rb + 0][kof];
            float4 v1 = *(const float4*)&hrec[rb + 1][kof];
            a00 += v0.x * w0.x + v0.y * w0.y + v0.z * w0.z + v0.w * w0.w;
            a01 += v0.x * w1.x + v0.y * w1.y + v0.z * w1.z + v0.w * w1.w;
            a10 += v1.x * w0.x + v1.y * w0.y + v1.z * w0.z + v1.w * w0.w;
            a11 += v1.x * w1.x + v1.y * w1.y + v1.z * w1.z + v1.w * w1.w;
        }

        // ---- (5) butterfly over 16 ks lanes (xor 1,2,4,8) ----
        #pragma unroll
        for (int m = 1; m <= 8; m <<= 1) {
            a00 += __shfl_xor(a00, m);
            a01 += __shfl_xor(a01, m);
            a10 += __shfl_xor(a10, m);
            a11 += __shfl_xor(a11, m);
        }
        // ---- exchange across gate-pair bit (xor 16): gh==0 gets o,chat ----
        float x00 = __shfl_xor(a00, 16);
        float x01 = __shfl_xor(a01, 16);
        float x10 = __shfl_xor(a10, 16);
        float x11 = __shfl_xor(a11, 16);

        // ---- (6) activations + publish (lanes gh==0 && ks<2: bl = rb+ks) ----
        if (gh == 0 && ks < 2) {
            const int bl = rb + ks;
            float iv = ks == 0 ? a00 : a10;
            float fv = ks == 0 ? a01 : a11;
            float ov = ks == 0 ? x00 : x10;
            float qv = ks == 0 ? x01 : x11;
            float ig = sigm(iv + bb[0]);
            float fg = sigm(fv + bb[1]);
            float og = sigm(ov + bb[2]);
            float ch = tanhf(qv + bb[3]);
            c_state = fg * c_state + ig * ch;
            float hn = og * tanhf(c_state);
            astore64(&ringOwn[(t & 1) * 1024 + bl * 256 + col],
                     ((ull)__float_as_uint(hn) << 32) | (ull)(uint)(t + 1));
            if (layer == 1) {
                const int bglob = grp * 4 + bl;
                out[((size_t)bglob * TT + t) * HH + col] = hn;
                if (t == TT - 1) {
                    float* tail = out + (size_t)BB * TT * HH;
                    tail[bglob * HH + col] = hn;                // hT (last layer)
                    tail[BB * HH + bglob * HH + col] = c_state; // cT (last layer)
                }
            }
        }
        __syncthreads();  // protect inp/hrec before next iteration overwrites
    }
}

extern "C" void kernel_launch(void* const* d_in, const int* in_sizes, int n_in,
                              void* d_out, int out_size, void* d_ws, size_t ws_size,
                              hipStream_t stream) {
    (void)in_sizes; (void)n_in; (void)out_size; (void)ws_size;
    const float* x    = (const float*)d_in[0];
    const float* W    = (const float*)d_in[1];
    const float* bias = (const float*)d_in[2];
    float* out  = (float*)d_out;
    int*   sync = (int*)d_ws;
    ull*   ring = (ull*)((char*)d_ws + 4096);  // 16 communities x 16 KB = 256 KB

    hipMemsetAsync(d_ws, 0, 4096 + 16 * 2048 * sizeof(ull), stream);  // markers + ring tags
    hipLaunchKernelGGL(lstm_scan, dim3(512), dim3(NT), 0, stream, x, W, bias, out, ring, sync);
}

// Round 14
// 8282.360 us; speedup vs baseline: 1.7658x; 1.7658x over previous
//
#include <hip/hip_runtime.h>

#define BB 32
#define TT 2048
#define HH 256
#define NT 512

typedef unsigned long long ull;
typedef unsigned int uint;

__device__ __forceinline__ float sigm(float v) { return 1.0f / (1.0f + __expf(-v)); }

__device__ __forceinline__ int aload(const int* p) {
  return __hip_atomic_load(p, __ATOMIC_RELAXED, __HIP_MEMORY_SCOPE_AGENT);
}
__device__ __forceinline__ void astore(int* p, int v) {
  __hip_atomic_store(p, v, __ATOMIC_RELAXED, __HIP_MEMORY_SCOPE_AGENT);
}
__device__ __forceinline__ ull aload64(const ull* p) {
  return __hip_atomic_load(p, __ATOMIC_RELAXED, __HIP_MEMORY_SCOPE_AGENT);
}
__device__ __forceinline__ void astore64(ull* p, ull v) {
  __hip_atomic_store(p, v, __ATOMIC_RELAXED, __HIP_MEMORY_SCOPE_AGENT);
}

// Round-12 shell (grid 256, 1 WG/CU, communities c = bid&7 = layer*4+grp, 32 WGs each,
// 8 batches, depth-2 tagged ring 2x2048 pairs + 32 markers) with a denser tile:
// per-thread 2 gates x 4 batches x K-slice 32. Lane map: ks = lane&15 (k = j*64+ks*4),
// gh = bit4 (0->{i,f}, 1->{o,chat}), bh = bit5 (batch half of 4). Weights 16 float4
// = 64 VGPR; 32 ds_read_b128/thread/step, 8 FMA each (2x round-12 ratio). Reduction:
// butterfly xor{1,2,4,8} over ks + xor16 gate-pair exchange. ~115 VGPR < 128 cap
// (r10/r11 lesson: spill shows as GB-scale FETCH_SIZE).
__global__ __launch_bounds__(NT) void lstm_scan(
    const float* __restrict__ x,     // [B,T,H]
    const float* __restrict__ W,     // [L,4,H,2H]
    const float* __restrict__ bias,  // [L,4,H]
    float* __restrict__ out,         // [B,T,H] + hT[B,H] + cT[B,H]
    ull* __restrict__ ring,
    int* __restrict__ sync)
{
    const int bid   = blockIdx.x;
    const int c     = bid & 7;        // community == XCD slot
    const int ug    = bid >> 3;       // 0..31
    const int layer = c >> 2;
    const int grp   = c & 3;          // batch group
    const int tid   = threadIdx.x;
    const int lane  = tid & 63;
    const int wave  = tid >> 6;       // col within group
    const int ks    = lane & 15;      // K-slice lane (bits 0-3)
    const int gh    = (lane >> 4) & 1;// gate pair: 0 -> {i,f}, 1 -> {o,chat}
    const int bh    = lane >> 5;      // batch half
    const int col   = ug * 8 + wave;
    const int rb    = bh * 4;         // local batch base (4 rows/thread)

    int* mOwn = sync + c * 32;
    int* mSib = sync + (4 + grp) * 32;             // layer-1 community, same grp
    ull* ringOwn = ring + (size_t)c * 4096;        // 2 slots x 2048
    ull* ringIn  = ring + (size_t)grp * 4096;      // layer-0 community, same grp

    __shared__ float inp[8][268];
    __shared__ float hrec[8][268];

    // weight-stationary: wA/wB[j] = W[l][gh*2 / gh*2+1][col][j*64 + ks*4 .. +3]
    float4 wA[8], wB[8];
    const float* WAp = W + (((size_t)layer * 4 + gh * 2)     * HH + col) * (2 * HH);
    const float* WBp = W + (((size_t)layer * 4 + gh * 2 + 1) * HH + col) * (2 * HH);
    #pragma unroll
    for (int j = 0; j < 8; ++j) {
        wA[j] = *(const float4*)(WAp + j * 64 + ks * 4);
        wB[j] = *(const float4*)(WBp + j * 64 + ks * 4);
    }

    float bb[4];
    #pragma unroll
    for (int g = 0; g < 4; ++g) bb[g] = bias[((size_t)layer * 4 + g) * HH + col];

    const int prow = tid >> 6;          // staging row (local batch), round-12 map
    const int pcol = (tid & 63) << 2;   // staging col base

    float c_state = 0.f;  // valid on publish lanes (gh==0 && ks<4): (bl = rb+ks, col)

    for (int t = 0; t < TT; ++t) {
        // ---- (1) input stage: x (layer0) or h0 ring poll (layer1), round-12 exact ----
        if (layer == 0) {
            *(float4*)&inp[prow][pcol] =
                *(const float4*)(x + ((size_t)(grp * 8 + prow) * TT + t) * HH + pcol);
        } else {
            const ull* rin = ringIn + (t & 1) * 2048 + 4 * tid;  // h0(t), tag t+1
            const uint want = (uint)(t + 1);
            uint pend = 0xFu; ull v[4];
            for (;;) {
                #pragma unroll
                for (int j = 0; j < 4; ++j)
                    if (pend & (1u << j)) v[j] = aload64(&rin[j]);
                #pragma unroll
                for (int j = 0; j < 4; ++j)
                    if ((pend & (1u << j)) && (uint)v[j] == want) {
                        inp[prow][pcol + j] = __uint_as_float((uint)(v[j] >> 32));
                        pend &= ~(1u << j);
                    }
                if (!pend) break;
                __builtin_amdgcn_s_sleep(1);
            }
        }
        __syncthreads();  // inp ready

        // ---- (2) recurrent poll -> hrec (4 pairs/thread, round-12 exact) ----
        {
            const ull* rr_ = ringOwn + ((t + 1) & 1) * 2048 + 4 * tid;  // h_l(t-1), tag t
            const uint want = (uint)t;
            uint pend = 0xFu; ull v[4];
            for (;;) {
                #pragma unroll
                for (int j = 0; j < 4; ++j)
                    if (pend & (1u << j)) v[j] = aload64(&rr_[j]);
                #pragma unroll
                for (int j = 0; j < 4; ++j)
                    if ((pend & (1u << j)) && (uint)v[j] == want) {
                        hrec[prow][pcol + j] = __uint_as_float((uint)(v[j] >> 32));
                        pend &= ~(1u << j);
                    }
                if (!pend) break;
                __builtin_amdgcn_s_sleep(1);
            }
        }
        // ---- (3) WAR gates (round-12 exact; overlaps stragglers) ----
        if (tid < 32)                    { while (aload(&mOwn[tid]) < t)          __builtin_amdgcn_s_sleep(1); }
        else if (layer == 0 && tid < 64) { while (aload(&mSib[tid - 32]) < t - 1) __builtin_amdgcn_s_sleep(1); }
        __syncthreads();  // hrec ready + gates passed
        if (tid == 0) astore(&mOwn[ug], t + 1);  // staged step t (inp + hrec consumed)

        // ---- (4) dot: 4 reads feed 32 FMA per j (4 rows x 2 gates x 4k) ----
        float aA0 = 0.f, aA1 = 0.f, aA2 = 0.f, aA3 = 0.f;
        float aB0 = 0.f, aB1 = 0.f, aB2 = 0.f, aB3 = 0.f;
        #pragma unroll
        for (int j = 0; j < 4; ++j) {
            const int kof = j * 64 + ks * 4;
            float4 w0 = wA[j], w1 = wB[j];
            float4 v0 = *(const float4*)&inp[rb + 0][kof];
            float4 v1 = *(const float4*)&inp[rb + 1][kof];
            float4 v2 = *(const float4*)&inp[rb + 2][kof];
            float4 v3 = *(const float4*)&inp[rb + 3][kof];
            aA0 += v0.x * w0.x + v0.y * w0.y + v0.z * w0.z + v0.w * w0.w;
            aB0 += v0.x * w1.x + v0.y * w1.y + v0.z * w1.z + v0.w * w1.w;
            aA1 += v1.x * w0.x + v1.y * w0.y + v1.z * w0.z + v1.w * w0.w;
            aB1 += v1.x * w1.x + v1.y * w1.y + v1.z * w1.z + v1.w * w1.w;
            aA2 += v2.x * w0.x + v2.y * w0.y + v2.z * w0.z + v2.w * w0.w;
            aB2 += v2.x * w1.x + v2.y * w1.y + v2.z * w1.z + v2.w * w1.w;
            aA3 += v3.x * w0.x + v3.y * w0.y + v3.z * w0.z + v3.w * w0.w;
            aB3 += v3.x * w1.x + v3.y * w1.y + v3.z * w1.z + v3.w * w1.w;
        }
        #pragma unroll
        for (int j = 4; j < 8; ++j) {
            const int kof = (j - 4) * 64 + ks * 4;
            float4 w0 = wA[j], w1 = wB[j];
            float4 v0 = *(const float4*)&hrec[rb + 0][kof];
            float4 v1 = *(const float4*)&hrec[rb + 1][kof];
            float4 v2 = *(const float4*)&hrec[rb + 2][kof];
            float4 v3 = *(const float4*)&hrec[rb + 3][kof];
            aA0 += v0.x * w0.x + v0.y * w0.y + v0.z * w0.z + v0.w * w0.w;
            aB0 += v0.x * w1.x + v0.y * w1.y + v0.z * w1.z + v0.w * w1.w;
            aA1 += v1.x * w0.x + v1.y * w0.y + v1.z * w0.z + v1.w * w0.w;
            aB1 += v1.x * w1.x + v1.y * w1.y + v1.z * w1.z + v1.w * w1.w;
            aA2 += v2.x * w0.x + v2.y * w0.y + v2.z * w0.z + v2.w * w0.w;
            aB2 += v2.x * w1.x + v2.y * w1.y + v2.z * w1.z + v2.w * w1.w;
            aA3 += v3.x * w0.x + v3.y * w0.y + v3.z * w0.z + v3.w * w0.w;
            aB3 += v3.x * w1.x + v3.y * w1.y + v3.z * w1.z + v3.w * w1.w;
        }

        // ---- (5) butterfly over 16 ks lanes (xor 1,2,4,8) ----
        #pragma unroll
        for (int m = 1; m <= 8; m <<= 1) {
            aA0 += __shfl_xor(aA0, m);
            aA1 += __shfl_xor(aA1, m);
            aA2 += __shfl_xor(aA2, m);
            aA3 += __shfl_xor(aA3, m);
            aB0 += __shfl_xor(aB0, m);
            aB1 += __shfl_xor(aB1, m);
            aB2 += __shfl_xor(aB2, m);
            aB3 += __shfl_xor(aB3, m);
        }
        // ---- gate-pair exchange (xor 16): on gh==0 lanes these are o,chat sums ----
        float oA0 = __shfl_xor(aA0, 16), oA1 = __shfl_xor(aA1, 16);
        float oA2 = __shfl_xor(aA2, 16), oA3 = __shfl_xor(aA3, 16);
        float qB0 = __shfl_xor(aB0, 16), qB1 = __shfl_xor(aB1, 16);
        float qB2 = __shfl_xor(aB2, 16), qB3 = __shfl_xor(aB3, 16);

        // ---- (6) activations + publish (lanes gh==0 && ks<4: bl = rb+ks) ----
        if (gh == 0 && ks < 4) {
            const int bl = rb + ks;
            float iv = ks == 0 ? aA0 : ks == 1 ? aA1 : ks == 2 ? aA2 : aA3;
            float fv = ks == 0 ? aB0 : ks == 1 ? aB1 : ks == 2 ? aB2 : aB3;
            float ov = ks == 0 ? oA0 : ks == 1 ? oA1 : ks == 2 ? oA2 : oA3;
            float qv = ks == 0 ? qB0 : ks == 1 ? qB1 : ks == 2 ? qB2 : qB3;
            float ig = sigm(iv + bb[0]);
            float fg = sigm(fv + bb[1]);
            float og = sigm(ov + bb[2]);
            float ch = tanhf(qv + bb[3]);
            c_state = fg * c_state + ig * ch;
            float hn = og * tanhf(c_state);
            astore64(&ringOwn[(t & 1) * 2048 + bl * 256 + col],
                     ((ull)__float_as_uint(hn) << 32) | (ull)(uint)(t + 1));
            if (layer == 1) {
                const int bglob = grp * 8 + bl;
                out[((size_t)bglob * TT + t) * HH + col] = hn;
                if (t == TT - 1) {
                    float* tail = out + (size_t)BB * TT * HH;
                    tail[bglob * HH + col] = hn;                // hT (last layer)
                    tail[BB * HH + bglob * HH + col] = c_state; // cT (last layer)
                }
            }
        }
        __syncthreads();  // protect inp/hrec before next iteration overwrites
    }
}

extern "C" void kernel_launch(void* const* d_in, const int* in_sizes, int n_in,
                              void* d_out, int out_size, void* d_ws, size_t ws_size,
                              hipStream_t stream) {
    (void)in_sizes; (void)n_in; (void)out_size; (void)ws_size;
    const float* x    = (const float*)d_in[0];
    const float* W    = (const float*)d_in[1];
    const float* bias = (const float*)d_in[2];
    float* out  = (float*)d_out;
    int*   sync = (int*)d_ws;
    ull*   ring = (ull*)((char*)d_ws + 4096);  // 8 communities x 32 KB = 256 KB

    hipMemsetAsync(d_ws, 0, 4096 + 8 * 4096 * sizeof(ull), stream);  // markers + ring tags
    hipLaunchKernelGGL(lstm_scan, dim3(256), dim3(NT), 0, stream, x, W, bias, out, ring, sync);
}

// Round 15
// 7130.826 us; speedup vs baseline: 2.0509x; 1.1615x over previous
//
#include <hip/hip_runtime.h>

#define BB 32
#define TT 2048
#define HH 256
#define NT 512

typedef unsigned long long ull;
typedef unsigned int uint;

__device__ __forceinline__ float sigm(float v) { return 1.0f / (1.0f + __expf(-v)); }

__device__ __forceinline__ int aload(const int* p) {
  return __hip_atomic_load(p, __ATOMIC_RELAXED, __HIP_MEMORY_SCOPE_AGENT);
}
__device__ __forceinline__ void astore(int* p, int v) {
  __hip_atomic_store(p, v, __ATOMIC_RELAXED, __HIP_MEMORY_SCOPE_AGENT);
}
__device__ __forceinline__ ull aload64(const ull* p) {
  return __hip_atomic_load(p, __ATOMIC_RELAXED, __HIP_MEMORY_SCOPE_AGENT);
}
__device__ __forceinline__ void astore64(ull* p, ull v) {
  __hip_atomic_store(p, v, __ATOMIC_RELAXED, __HIP_MEMORY_SCOPE_AGENT);
}

// r12 shell: grid 256, communities c = bid&7 = layer*4+grp (XCD-aligned), 32 WGs x 8
// batches. r14 tile: per-thread 2 gates x 4 batches x K-slice 32 (ks=lane&15, gh=bit4,
// bh=bit5), weights 16 float4 = 64 VGPR.
// NEW (de-serialization):
//  - depth-4 ring: 4 slots x 2048 pairs {tag, hbits}; publish slot t&3. WAR thresholds
//    own>=t-2 / sib>=t-3 -> markers are 2-3 steps stale, first read passes; gate loads
//    issued at step start, verified after the h-poll (hidden).
//  - x-dot BEFORE h-poll: h(t-1) publish->visibility hides under x compute.
//  - staging map p = tid + 512*j: lane-consecutive LDS cols (conflict-free writes,
//    was 8-way -> 1.5e8 conflicts) + coalesced ring loads.
__global__ __launch_bounds__(NT) void lstm_scan(
    const float* __restrict__ x,     // [B,T,H]
    const float* __restrict__ W,     // [L,4,H,2H]
    const float* __restrict__ bias,  // [L,4,H]
    float* __restrict__ out,         // [B,T,H] + hT[B,H] + cT[B,H]
    ull* __restrict__ ring,
    int* __restrict__ sync)
{
    const int bid   = blockIdx.x;
    const int c     = bid & 7;        // community == XCD slot
    const int ug    = bid >> 3;       // 0..31
    const int layer = c >> 2;
    const int grp   = c & 3;          // batch group
    const int tid   = threadIdx.x;
    const int lane  = tid & 63;
    const int wave  = tid >> 6;       // col within group
    const int ks    = lane & 15;      // K-slice lane (bits 0-3)
    const int gh    = (lane >> 4) & 1;// gate pair: 0 -> {i,f}, 1 -> {o,chat}
    const int bh    = lane >> 5;      // batch half
    const int col   = ug * 8 + wave;
    const int rb    = bh * 4;         // local batch base (4 rows/thread)

    int* mOwn = sync + c * 32;
    int* mSib = sync + (4 + grp) * 32;             // layer-1 community, same grp
    ull* ringOwn = ring + (size_t)c * 8192;        // 4 slots x 2048
    ull* ringIn  = ring + (size_t)grp * 8192;      // layer-0 community, same grp

    __shared__ float inp[8][268];
    __shared__ float hrec[8][268];

    // weight-stationary: wA/wB[j] = W[l][gh*2 / gh*2+1][col][j*64 + ks*4 .. +3]
    float4 wA[8], wB[8];
    const float* WAp = W + (((size_t)layer * 4 + gh * 2)     * HH + col) * (2 * HH);
    const float* WBp = W + (((size_t)layer * 4 + gh * 2 + 1) * HH + col) * (2 * HH);
    #pragma unroll
    for (int j = 0; j < 8; ++j) {
        wA[j] = *(const float4*)(WAp + j * 64 + ks * 4);
        wB[j] = *(const float4*)(WBp + j * 64 + ks * 4);
    }

    float bb[4];
    #pragma unroll
    for (int g = 0; g < 4; ++g) bb[g] = bias[((size_t)layer * 4 + g) * HH + col];

    const int srow = tid >> 8;        // staging row base (0/1), rows srow+2j
    const int scol = tid & 255;       // staging col (lane-consecutive)

    float c_state = 0.f;  // valid on publish lanes (gh==0 && ks<4): (bl = rb+ks, col)

    for (int t = 0; t < TT; ++t) {
        // ---- (0) WAR-gate pre-read (stale-friendly with depth-4; verified later) ----
        int gv = 0x7fffffff;
        if (tid < 32)                    gv = aload(&mOwn[tid]);
        else if (layer == 0 && tid < 64) gv = aload(&mSib[tid - 32]);

        // ---- (1) input stage: x (layer0) or h0 ring poll (layer1) ----
        if (layer == 0) {
            #pragma unroll
            for (int j = 0; j < 4; ++j) {
                const int row = srow + 2 * j;
                inp[row][scol] = x[((size_t)(grp * 8 + row) * TT + t) * HH + scol];
            }
        } else {
            const ull* rin = ringIn + (t & 3) * 2048;  // h0(t), tag t+1
            const uint want = (uint)(t + 1);
            uint pend = 0xFu; ull v[4];
            for (;;) {
                #pragma unroll
                for (int j = 0; j < 4; ++j)
                    if (pend & (1u << j)) v[j] = aload64(&rin[tid + 512 * j]);
                #pragma unroll
                for (int j = 0; j < 4; ++j)
                    if ((pend & (1u << j)) && (uint)v[j] == want) {
                        inp[srow + 2 * j][scol] = __uint_as_float((uint)(v[j] >> 32));
                        pend &= ~(1u << j);
                    }
                if (!pend) break;
                __builtin_amdgcn_s_sleep(1);
            }
        }
        __syncthreads();  // inp ready

        // ---- (2) x-part dot (K=0..255) — h(t-1) visibility hides under this ----
        float aA0 = 0.f, aA1 = 0.f, aA2 = 0.f, aA3 = 0.f;
        float aB0 = 0.f, aB1 = 0.f, aB2 = 0.f, aB3 = 0.f;
        #pragma unroll
        for (int j = 0; j < 4; ++j) {
            const int kof = j * 64 + ks * 4;
            float4 w0 = wA[j], w1 = wB[j];
            float4 v0 = *(const float4*)&inp[rb + 0][kof];
            float4 v1 = *(const float4*)&inp[rb + 1][kof];
            float4 v2 = *(const float4*)&inp[rb + 2][kof];
            float4 v3 = *(const float4*)&inp[rb + 3][kof];
            aA0 += v0.x * w0.x + v0.y * w0.y + v0.z * w0.z + v0.w * w0.w;
            aB0 += v0.x * w1.x + v0.y * w1.y + v0.z * w1.z + v0.w * w1.w;
            aA1 += v1.x * w0.x + v1.y * w0.y + v1.z * w0.z + v1.w * w0.w;
            aB1 += v1.x * w1.x + v1.y * w1.y + v1.z * w1.z + v1.w * w1.w;
            aA2 += v2.x * w0.x + v2.y * w0.y + v2.z * w0.z + v2.w * w0.w;
            aB2 += v2.x * w1.x + v2.y * w1.y + v2.z * w1.z + v2.w * w1.w;
            aA3 += v3.x * w0.x + v3.y * w0.y + v3.z * w0.z + v3.w * w0.w;
            aB3 += v3.x * w1.x + v3.y * w1.y + v3.z * w1.z + v3.w * w1.w;
        }

        // ---- (3) recurrent poll -> hrec (slot (t-1)&3, tag t) ----
        {
            const ull* rr_ = ringOwn + ((t + 3) & 3) * 2048;
            const uint want = (uint)t;
            uint pend = 0xFu; ull v[4];
            for (;;) {
                #pragma unroll
                for (int j = 0; j < 4; ++j)
                    if (pend & (1u << j)) v[j] = aload64(&rr_[tid + 512 * j]);
                #pragma unroll
                for (int j = 0; j < 4; ++j)
                    if ((pend & (1u << j)) && (uint)v[j] == want) {
                        hrec[srow + 2 * j][scol] = __uint_as_float((uint)(v[j] >> 32));
                        pend &= ~(1u << j);
                    }
                if (!pend) break;
                __builtin_amdgcn_s_sleep(1);
            }
        }
        // ---- (4) WAR-gate verify (first read passes in steady state) ----
        if (tid < 32) {
            while (gv < t - 2) { __builtin_amdgcn_s_sleep(1); gv = aload(&mOwn[tid]); }
        } else if (layer == 0 && tid < 64) {
            while (gv < t - 3) { __builtin_amdgcn_s_sleep(1); gv = aload(&mSib[tid - 32]); }
        }
        __syncthreads();  // hrec ready + gate passed
        if (tid == 0) astore(&mOwn[ug], t + 1);  // staged step t (inp + hrec in LDS)

        // ---- (5) h-part dot (K=256..511) ----
        #pragma unroll
        for (int j = 4; j < 8; ++j) {
            const int kof = (j - 4) * 64 + ks * 4;
            float4 w0 = wA[j], w1 = wB[j];
            float4 v0 = *(const float4*)&hrec[rb + 0][kof];
            float4 v1 = *(const float4*)&hrec[rb + 1][kof];
            float4 v2 = *(const float4*)&hrec[rb + 2][kof];
            float4 v3 = *(const float4*)&hrec[rb + 3][kof];
            aA0 += v0.x * w0.x + v0.y * w0.y + v0.z * w0.z + v0.w * w0.w;
            aB0 += v0.x * w1.x + v0.y * w1.y + v0.z * w1.z + v0.w * w1.w;
            aA1 += v1.x * w0.x + v1.y * w0.y + v1.z * w0.z + v1.w * w0.w;
            aB1 += v1.x * w1.x + v1.y * w1.y + v1.z * w1.z + v1.w * w1.w;
            aA2 += v2.x * w0.x + v2.y * w0.y + v2.z * w0.z + v2.w * w0.w;
            aB2 += v2.x * w1.x + v2.y * w1.y + v2.z * w1.z + v2.w * w1.w;
            aA3 += v3.x * w0.x + v3.y * w0.y + v3.z * w0.z + v3.w * w0.w;
            aB3 += v3.x * w1.x + v3.y * w1.y + v3.z * w1.z + v3.w * w1.w;
        }

        // ---- (6) butterfly over 16 ks lanes (xor 1,2,4,8) ----
        #pragma unroll
        for (int m = 1; m <= 8; m <<= 1) {
            aA0 += __shfl_xor(aA0, m);
            aA1 += __shfl_xor(aA1, m);
            aA2 += __shfl_xor(aA2, m);
            aA3 += __shfl_xor(aA3, m);
            aB0 += __shfl_xor(aB0, m);
            aB1 += __shfl_xor(aB1, m);
            aB2 += __shfl_xor(aB2, m);
            aB3 += __shfl_xor(aB3, m);
        }
        // ---- gate-pair exchange (xor 16): on gh==0 lanes these are o,chat sums ----
        float oA0 = __shfl_xor(aA0, 16), oA1 = __shfl_xor(aA1, 16);
        float oA2 = __shfl_xor(aA2, 16), oA3 = __shfl_xor(aA3, 16);
        float qB0 = __shfl_xor(aB0, 16), qB1 = __shfl_xor(aB1, 16);
        float qB2 = __shfl_xor(aB2, 16), qB3 = __shfl_xor(aB3, 16);

        // ---- (7) activations + publish (lanes gh==0 && ks<4: bl = rb+ks) ----
        if (gh == 0 && ks < 4) {
            const int bl = rb + ks;
            float iv = ks == 0 ? aA0 : ks == 1 ? aA1 : ks == 2 ? aA2 : aA3;
            float fv = ks == 0 ? aB0 : ks == 1 ? aB1 : ks == 2 ? aB2 : aB3;
            float ov = ks == 0 ? oA0 : ks == 1 ? oA1 : ks == 2 ? oA2 : oA3;
            float qv = ks == 0 ? qB0 : ks == 1 ? qB1 : ks == 2 ? qB2 : qB3;
            float ig = sigm(iv + bb[0]);
            float fg = sigm(fv + bb[1]);
            float og = sigm(ov + bb[2]);
            float ch = tanhf(qv + bb[3]);
            c_state = fg * c_state + ig * ch;
            float hn = og * tanhf(c_state);
            astore64(&ringOwn[(t & 3) * 2048 + bl * 256 + col],
                     ((ull)__float_as_uint(hn) << 32) | (ull)(uint)(t + 1));
            if (layer == 1) {
                const int bglob = grp * 8 + bl;
                out[((size_t)bglob * TT + t) * HH + col] = hn;
                if (t == TT - 1) {
                    float* tail = out + (size_t)BB * TT * HH;
                    tail[bglob * HH + col] = hn;                // hT (last layer)
                    tail[BB * HH + bglob * HH + col] = c_state; // cT (last layer)
                }
            }
        }
        __syncthreads();  // protect inp/hrec before next iteration overwrites
    }
}

extern "C" void kernel_launch(void* const* d_in, const int* in_sizes, int n_in,
                              void* d_out, int out_size, void* d_ws, size_t ws_size,
                              hipStream_t stream) {
    (void)in_sizes; (void)n_in; (void)out_size; (void)ws_size;
    const float* x    = (const float*)d_in[0];
    const float* W    = (const float*)d_in[1];
    const float* bias = (const float*)d_in[2];
    float* out  = (float*)d_out;
    int*   sync = (int*)d_ws;
    ull*   ring = (ull*)((char*)d_ws + 4096);  // 8 communities x 64 KB = 512 KB

    hipMemsetAsync(d_ws, 0, 4096 + 8 * 8192 * sizeof(ull), stream);  // markers + ring tags
    hipLaunchKernelGGL(lstm_scan, dim3(256), dim3(NT), 0, stream, x, W, bias, out, ring, sync);
}

// Round 16
// 6401.358 us; speedup vs baseline: 2.2846x; 1.1140x over previous
//
#include <hip/hip_runtime.h>

#define BB 32
#define TT 2048
#define HH 256
#define NT 512

typedef unsigned long long ull;
typedef unsigned int uint;

__device__ __forceinline__ float sigm(float v) { return 1.0f / (1.0f + __expf(-v)); }

__device__ __forceinline__ int aload(const int* p) {
  return __hip_atomic_load(p, __ATOMIC_RELAXED, __HIP_MEMORY_SCOPE_AGENT);
}
__device__ __forceinline__ void astore(int* p, int v) {
  __hip_atomic_store(p, v, __ATOMIC_RELAXED, __HIP_MEMORY_SCOPE_AGENT);
}
__device__ __forceinline__ ull aload64(const ull* p) {
  return __hip_atomic_load(p, __ATOMIC_RELAXED, __HIP_MEMORY_SCOPE_AGENT);
}
__device__ __forceinline__ void astore64(ull* p, ull v) {
  __hip_atomic_store(p, v, __ATOMIC_RELAXED, __HIP_MEMORY_SCOPE_AGENT);
}

// r15 shell (grid 256, communities c = bid&7 = layer*4+grp, 32 WGs x 8 batches,
// depth-4 tagged ring, stale-friendly WAR gates, conflict-free staging map) with:
//  - double-buffered inp/hrec LDS -> end-of-loop barrier DELETED (2 barriers/step).
//    Safety: with 2 barriers no thread can lap a buffer; publisher lanes run ahead.
//  - x register-prefetch: x(t+1) loaded into 4 named scalars during step t; staging
//    is pure LDS writes (no HBM latency feeding barrier 1).
//  - polls spin 4 sweeps before s_sleep.
__global__ __launch_bounds__(NT) void lstm_scan(
    const float* __restrict__ x,     // [B,T,H]
    const float* __restrict__ W,     // [L,4,H,2H]
    const float* __restrict__ bias,  // [L,4,H]
    float* __restrict__ out,         // [B,T,H] + hT[B,H] + cT[B,H]
    ull* __restrict__ ring,
    int* __restrict__ sync)
{
    const int bid   = blockIdx.x;
    const int c     = bid & 7;        // community == XCD slot
    const int ug    = bid >> 3;       // 0..31
    const int layer = c >> 2;
    const int grp   = c & 3;          // batch group
    const int tid   = threadIdx.x;
    const int lane  = tid & 63;
    const int wave  = tid >> 6;       // col within group
    const int ks    = lane & 15;      // K-slice lane (bits 0-3)
    const int gh    = (lane >> 4) & 1;// gate pair: 0 -> {i,f}, 1 -> {o,chat}
    const int bh    = lane >> 5;      // batch half
    const int col   = ug * 8 + wave;
    const int rb    = bh * 4;         // local batch base (4 rows/thread)

    int* mOwn = sync + c * 32;
    int* mSib = sync + (4 + grp) * 32;             // layer-1 community, same grp
    ull* ringOwn = ring + (size_t)c * 8192;        // 4 slots x 2048
    ull* ringIn  = ring + (size_t)grp * 8192;      // layer-0 community, same grp

    __shared__ float inp[2][8][268];
    __shared__ float hrec[2][8][268];

    // weight-stationary: wA/wB[j] = W[l][gh*2 / gh*2+1][col][j*64 + ks*4 .. +3]
    float4 wA[8], wB[8];
    const float* WAp = W + (((size_t)layer * 4 + gh * 2)     * HH + col) * (2 * HH);
    const float* WBp = W + (((size_t)layer * 4 + gh * 2 + 1) * HH + col) * (2 * HH);
    #pragma unroll
    for (int j = 0; j < 8; ++j) {
        wA[j] = *(const float4*)(WAp + j * 64 + ks * 4);
        wB[j] = *(const float4*)(WBp + j * 64 + ks * 4);
    }

    float bb[4];
    #pragma unroll
    for (int g = 0; g < 4; ++g) bb[g] = bias[((size_t)layer * 4 + g) * HH + col];

    const int srow = tid >> 8;        // staging row base (0/1), rows srow+2j
    const int scol = tid & 255;       // staging col (lane-consecutive)

    // x prefetch regs (layer 0 only): hold x(t) rows srow+{0,2,4,6}
    float xr0 = 0.f, xr1 = 0.f, xr2 = 0.f, xr3 = 0.f;
    if (layer == 0) {
        const float* xb = x + (size_t)(grp * 8 + srow) * TT * HH + scol;
        xr0 = xb[0 * 2 * TT * HH];
        xr1 = xb[1 * 2 * TT * HH];
        xr2 = xb[2 * 2 * TT * HH];
        xr3 = xb[3 * 2 * TT * HH];
    }

    float c_state = 0.f;  // valid on publish lanes (gh==0 && ks<4): (bl = rb+ks, col)

    for (int t = 0; t < TT; ++t) {
        const int p = t & 1;
        // ---- (0) WAR-gate pre-read (stale-friendly with depth-4; verified later) ----
        int gv = 0x7fffffff;
        if (tid < 32)                    gv = aload(&mOwn[tid]);
        else if (layer == 0 && tid < 64) gv = aload(&mSib[tid - 32]);

        // ---- (1) input stage: x from regs (layer0) or h0 ring poll (layer1) ----
        if (layer == 0) {
            inp[p][srow + 0][scol] = xr0;
            inp[p][srow + 2][scol] = xr1;
            inp[p][srow + 4][scol] = xr2;
            inp[p][srow + 6][scol] = xr3;
            const int tn = (t + 1 < TT) ? t + 1 : t;
            const float* xb = x + ((size_t)(grp * 8 + srow) * TT + tn) * HH + scol;
            xr0 = xb[0 * 2 * TT * HH];
            xr1 = xb[1 * 2 * TT * HH];
            xr2 = xb[2 * 2 * TT * HH];
            xr3 = xb[3 * 2 * TT * HH];
        } else {
            const ull* rin = ringIn + (t & 3) * 2048;  // h0(t), tag t+1
            const uint want = (uint)(t + 1);
            uint pend = 0xFu; ull v[4]; int tries = 0;
            for (;;) {
                #pragma unroll
                for (int j = 0; j < 4; ++j)
                    if (pend & (1u << j)) v[j] = aload64(&rin[tid + 512 * j]);
                #pragma unroll
                for (int j = 0; j < 4; ++j)
                    if ((pend & (1u << j)) && (uint)v[j] == want) {
                        inp[p][srow + 2 * j][scol] = __uint_as_float((uint)(v[j] >> 32));
                        pend &= ~(1u << j);
                    }
                if (!pend) break;
                if (++tries > 4) __builtin_amdgcn_s_sleep(1);
            }
        }
        __syncthreads();  // barrier 1: inp[p] ready

        // ---- (2) x-part dot (K=0..255) — h(t-1) visibility hides under this ----
        float aA0 = 0.f, aA1 = 0.f, aA2 = 0.f, aA3 = 0.f;
        float aB0 = 0.f, aB1 = 0.f, aB2 = 0.f, aB3 = 0.f;
        #pragma unroll
        for (int j = 0; j < 4; ++j) {
            const int kof = j * 64 + ks * 4;
            float4 w0 = wA[j], w1 = wB[j];
            float4 v0 = *(const float4*)&inp[p][rb + 0][kof];
            float4 v1 = *(const float4*)&inp[p][rb + 1][kof];
            float4 v2 = *(const float4*)&inp[p][rb + 2][kof];
            float4 v3 = *(const float4*)&inp[p][rb + 3][kof];
            aA0 += v0.x * w0.x + v0.y * w0.y + v0.z * w0.z + v0.w * w0.w;
            aB0 += v0.x * w1.x + v0.y * w1.y + v0.z * w1.z + v0.w * w1.w;
            aA1 += v1.x * w0.x + v1.y * w0.y + v1.z * w0.z + v1.w * w0.w;
            aB1 += v1.x * w1.x + v1.y * w1.y + v1.z * w1.z + v1.w * w1.w;
            aA2 += v2.x * w0.x + v2.y * w0.y + v2.z * w0.z + v2.w * w0.w;
            aB2 += v2.x * w1.x + v2.y * w1.y + v2.z * w1.z + v2.w * w1.w;
            aA3 += v3.x * w0.x + v3.y * w0.y + v3.z * w0.z + v3.w * w0.w;
            aB3 += v3.x * w1.x + v3.y * w1.y + v3.z * w1.z + v3.w * w1.w;
        }

        // ---- (3) recurrent poll -> hrec[p] (slot (t-1)&3, tag t) ----
        {
            const ull* rr_ = ringOwn + ((t + 3) & 3) * 2048;
            const uint want = (uint)t;
            uint pend = 0xFu; ull v[4]; int tries = 0;
            for (;;) {
                #pragma unroll
                for (int j = 0; j < 4; ++j)
                    if (pend & (1u << j)) v[j] = aload64(&rr_[tid + 512 * j]);
                #pragma unroll
                for (int j = 0; j < 4; ++j)
                    if ((pend & (1u << j)) && (uint)v[j] == want) {
                        hrec[p][srow + 2 * j][scol] = __uint_as_float((uint)(v[j] >> 32));
                        pend &= ~(1u << j);
                    }
                if (!pend) break;
                if (++tries > 4) __builtin_amdgcn_s_sleep(1);
            }
        }
        // ---- (4) WAR-gate verify (first read passes in steady state) ----
        if (tid < 32) {
            while (gv < t - 2) { __builtin_amdgcn_s_sleep(1); gv = aload(&mOwn[tid]); }
        } else if (layer == 0 && tid < 64) {
            while (gv < t - 3) { __builtin_amdgcn_s_sleep(1); gv = aload(&mSib[tid - 32]); }
        }
        __syncthreads();  // barrier 2: hrec[p] ready + gate passed
        if (tid == 0) astore(&mOwn[ug], t + 1);  // staged step t (inp + hrec in LDS)

        // ---- (5) h-part dot (K=256..511) ----
        #pragma unroll
        for (int j = 4; j < 8; ++j) {
            const int kof = (j - 4) * 64 + ks * 4;
            float4 w0 = wA[j], w1 = wB[j];
            float4 v0 = *(const float4*)&hrec[p][rb + 0][kof];
            float4 v1 = *(const float4*)&hrec[p][rb + 1][kof];
            float4 v2 = *(const float4*)&hrec[p][rb + 2][kof];
            float4 v3 = *(const float4*)&hrec[p][rb + 3][kof];
            aA0 += v0.x * w0.x + v0.y * w0.y + v0.z * w0.z + v0.w * w0.w;
            aB0 += v0.x * w1.x + v0.y * w1.y + v0.z * w1.z + v0.w * w1.w;
            aA1 += v1.x * w0.x + v1.y * w0.y + v1.z * w0.z + v1.w * w0.w;
            aB1 += v1.x * w1.x + v1.y * w1.y + v1.z * w1.z + v1.w * w1.w;
            aA2 += v2.x * w0.x + v2.y * w0.y + v2.z * w0.z + v2.w * w0.w;
            aB2 += v2.x * w1.x + v2.y * w1.y + v2.z * w1.z + v2.w * w1.w;
            aA3 += v3.x * w0.x + v3.y * w0.y + v3.z * w0.z + v3.w * w0.w;
            aB3 += v3.x * w1.x + v3.y * w1.y + v3.z * w1.z + v3.w * w1.w;
        }

        // ---- (6) butterfly over 16 ks lanes (xor 1,2,4,8) ----
        #pragma unroll
        for (int m = 1; m <= 8; m <<= 1) {
            aA0 += __shfl_xor(aA0, m);
            aA1 += __shfl_xor(aA1, m);
            aA2 += __shfl_xor(aA2, m);
            aA3 += __shfl_xor(aA3, m);
            aB0 += __shfl_xor(aB0, m);
            aB1 += __shfl_xor(aB1, m);
            aB2 += __shfl_xor(aB2, m);
            aB3 += __shfl_xor(aB3, m);
        }
        // ---- gate-pair exchange (xor 16): on gh==0 lanes these are o,chat sums ----
        float oA0 = __shfl_xor(aA0, 16), oA1 = __shfl_xor(aA1, 16);
        float oA2 = __shfl_xor(aA2, 16), oA3 = __shfl_xor(aA3, 16);
        float qB0 = __shfl_xor(aB0, 16), qB1 = __shfl_xor(aB1, 16);
        float qB2 = __shfl_xor(aB2, 16), qB3 = __shfl_xor(aB3, 16);

        // ---- (7) activations + publish (lanes gh==0 && ks<4: bl = rb+ks) ----
        if (gh == 0 && ks < 4) {
            const int bl = rb + ks;
            float iv = ks == 0 ? aA0 : ks == 1 ? aA1 : ks == 2 ? aA2 : aA3;
            float fv = ks == 0 ? aB0 : ks == 1 ? aB1 : ks == 2 ? aB2 : aB3;
            float ov = ks == 0 ? oA0 : ks == 1 ? oA1 : ks == 2 ? oA2 : oA3;
            float qv = ks == 0 ? qB0 : ks == 1 ? qB1 : ks == 2 ? qB2 : qB3;
            float ig = sigm(iv + bb[0]);
            float fg = sigm(fv + bb[1]);
            float og = sigm(ov + bb[2]);
            float ch = tanhf(qv + bb[3]);
            c_state = fg * c_state + ig * ch;
            float hn = og * tanhf(c_state);
            astore64(&ringOwn[(t & 3) * 2048 + bl * 256 + col],
                     ((ull)__float_as_uint(hn) << 32) | (ull)(uint)(t + 1));
            if (layer == 1) {
                const int bglob = grp * 8 + bl;
                out[((size_t)bglob * TT + t) * HH + col] = hn;
                if (t == TT - 1) {
                    float* tail = out + (size_t)BB * TT * HH;
                    tail[bglob * HH + col] = hn;                // hT (last layer)
                    tail[BB * HH + bglob * HH + col] = c_state; // cT (last layer)
                }
            }
        }
        // no end barrier: inp/hrec double-buffered; next step writes buffer p^1
    }
}

extern "C" void kernel_launch(void* const* d_in, const int* in_sizes, int n_in,
                              void* d_out, int out_size, void* d_ws, size_t ws_size,
                              hipStream_t stream) {
    (void)in_sizes; (void)n_in; (void)out_size; (void)ws_size;
    const float* x    = (const float*)d_in[0];
    const float* W    = (const float*)d_in[1];
    const float* bias = (const float*)d_in[2];
    float* out  = (float*)d_out;
    int*   sync = (int*)d_ws;
    ull*   ring = (ull*)((char*)d_ws + 4096);  // 8 communities x 64 KB = 512 KB

    hipMemsetAsync(d_ws, 0, 4096 + 8 * 8192 * sizeof(ull), stream);  // markers + ring tags
    hipLaunchKernelGGL(lstm_scan, dim3(256), dim3(NT), 0, stream, x, W, bias, out, ring, sync);
}

// Round 17
// 5912.703 us; speedup vs baseline: 2.4735x; 1.0826x over previous
//
#include <hip/hip_runtime.h>

#define BB 32
#define TT 2048
#define HH 256
#define NT 512

typedef unsigned long long ull;
typedef unsigned int uint;

__device__ __forceinline__ float sigm(float v) { return 1.0f / (1.0f + __expf(-v)); }

__device__ __forceinline__ int aload(const int* p) {
  return __hip_atomic_load(p, __ATOMIC_RELAXED, __HIP_MEMORY_SCOPE_AGENT);
}
__device__ __forceinline__ void astore(int* p, int v) {
  __hip_atomic_store(p, v, __ATOMIC_RELAXED, __HIP_MEMORY_SCOPE_AGENT);
}
__device__ __forceinline__ ull aload64(const ull* p) {
  return __hip_atomic_load(p, __ATOMIC_RELAXED, __HIP_MEMORY_SCOPE_AGENT);
}
__device__ __forceinline__ void astore64(ull* p, ull v) {
  __hip_atomic_store(p, v, __ATOMIC_RELAXED, __HIP_MEMORY_SCOPE_AGENT);
}

// Community degree 16: c = layer*8 + grp, grp = bid&7 (XCD slot; both layers of a grp
// share the slot), 16 WGs x 16 cols x 4 batches. Ring: 4 slots x 1024 pairs
// {tag(lo32), hbits(hi32)}, idx = bl*256 + col; 32 KB/community, 512 KB total.
// Lane map: ks = lane&15 (Kslice 32, k = j*64+ks*4), gh = bit4 (gate pair), cp = bit5
// (col select; col = ug*16 + wave*2 + cp); batches_t = 4 (rows 0..3). Weights 16 float4
// = 64 VGPR (128-cap safe). Carried from r15/16: depth-4 ring + stale WAR pre-read/
// verify (own>=t-2, sib>=t-3), double-buffered inp/hrec (2 barriers/step, no end
// barrier), x register-prefetch, spin-4-then-sleep polls, conflict-free staging map.
__global__ __launch_bounds__(NT) void lstm_scan(
    const float* __restrict__ x,     // [B,T,H]
    const float* __restrict__ W,     // [L,4,H,2H]
    const float* __restrict__ bias,  // [L,4,H]
    float* __restrict__ out,         // [B,T,H] + hT[B,H] + cT[B,H]
    ull* __restrict__ ring,
    int* __restrict__ sync)
{
    const int bid   = blockIdx.x;
    const int grp   = bid & 7;        // batch group (4 batches) == XCD slot
    const int layer = (bid >> 3) & 1;
    const int ug    = bid >> 4;       // 0..15
    const int c     = layer * 8 + grp;
    const int tid   = threadIdx.x;
    const int lane  = tid & 63;
    const int wave  = tid >> 6;       // 0..7
    const int ks    = lane & 15;      // K-slice lane (bits 0-3)
    const int gh    = (lane >> 4) & 1;// gate pair: 0 -> {i,f}, 1 -> {o,chat}
    const int cp    = lane >> 5;      // col select (bit 5)
    const int col   = ug * 16 + wave * 2 + cp;

    int* mOwn = sync + c * 16;
    int* mSib = sync + (8 + grp) * 16;             // layer-1 community, same grp
    ull* ringOwn = ring + (size_t)c * 4096;        // 4 slots x 1024
    ull* ringIn  = ring + (size_t)grp * 4096;      // layer-0 community, same grp

    __shared__ float inp[2][4][260];
    __shared__ float hrec[2][4][260];

    // weight-stationary: wA/wB[j] = W[l][gh*2 / gh*2+1][col][j*64 + ks*4 .. +3]
    float4 wA[8], wB[8];
    const float* WAp = W + (((size_t)layer * 4 + gh * 2)     * HH + col) * (2 * HH);
    const float* WBp = W + (((size_t)layer * 4 + gh * 2 + 1) * HH + col) * (2 * HH);
    #pragma unroll
    for (int j = 0; j < 8; ++j) {
        wA[j] = *(const float4*)(WAp + j * 64 + ks * 4);
        wB[j] = *(const float4*)(WBp + j * 64 + ks * 4);
    }

    float bb[4];
    #pragma unroll
    for (int g = 0; g < 4; ++g) bb[g] = bias[((size_t)layer * 4 + g) * HH + col];

    const int srow = tid >> 8;        // staging rows srow, srow+2
    const int scol = tid & 255;       // staging col (lane-consecutive)

    // x prefetch regs (layer 0): rows grp*4+srow, grp*4+srow+2 at col scol
    float xr0 = 0.f, xr1 = 0.f;
    if (layer == 0) {
        const float* xb = x + (size_t)(grp * 4 + srow) * TT * HH + scol;
        xr0 = xb[0];
        xr1 = xb[2 * TT * HH];
    }

    float c_state = 0.f;  // valid on publish lanes (gh==0 && ks<4): (bl = ks, col)

    for (int t = 0; t < TT; ++t) {
        const int p = t & 1;
        // ---- (0) WAR-gate pre-read (stale-friendly with depth-4; verified later) ----
        int gv = 0x7fffffff;
        if (tid < 16)                    gv = aload(&mOwn[tid]);
        else if (layer == 0 && tid < 48) { if (tid >= 32) gv = aload(&mSib[tid - 32]); }

        // ---- (1) input stage: x from regs (layer0) or h0 ring poll (layer1) ----
        if (layer == 0) {
            inp[p][srow + 0][scol] = xr0;
            inp[p][srow + 2][scol] = xr1;
            const int tn = (t + 1 < TT) ? t + 1 : t;
            const float* xb = x + ((size_t)(grp * 4 + srow) * TT + tn) * HH + scol;
            xr0 = xb[0];
            xr1 = xb[2 * TT * HH];
        } else {
            const ull* rin = ringIn + (t & 3) * 1024;  // h0(t), tag t+1
            const uint want = (uint)(t + 1);
            uint pend = 0x3u; ull v0, v1; int tries = 0;
            for (;;) {
                if (pend & 1u) v0 = aload64(&rin[tid]);
                if (pend & 2u) v1 = aload64(&rin[tid + 512]);
                if ((pend & 1u) && (uint)v0 == want) {
                    inp[p][srow][scol] = __uint_as_float((uint)(v0 >> 32));
                    pend &= ~1u;
                }
                if ((pend & 2u) && (uint)v1 == want) {
                    inp[p][srow + 2][scol] = __uint_as_float((uint)(v1 >> 32));
                    pend &= ~2u;
                }
                if (!pend) break;
                if (++tries > 4) __builtin_amdgcn_s_sleep(1);
            }
        }
        __syncthreads();  // barrier 1: inp[p] ready

        // ---- (2) x-part dot (K=0..255) — h(t-1) visibility hides under this ----
        float aA0 = 0.f, aA1 = 0.f, aA2 = 0.f, aA3 = 0.f;
        float aB0 = 0.f, aB1 = 0.f, aB2 = 0.f, aB3 = 0.f;
        #pragma unroll
        for (int j = 0; j < 4; ++j) {
            const int kof = j * 64 + ks * 4;
            float4 w0 = wA[j], w1 = wB[j];
            float4 v0 = *(const float4*)&inp[p][0][kof];
            float4 v1 = *(const float4*)&inp[p][1][kof];
            float4 v2 = *(const float4*)&inp[p][2][kof];
            float4 v3 = *(const float4*)&inp[p][3][kof];
            aA0 += v0.x * w0.x + v0.y * w0.y + v0.z * w0.z + v0.w * w0.w;
            aB0 += v0.x * w1.x + v0.y * w1.y + v0.z * w1.z + v0.w * w1.w;
            aA1 += v1.x * w0.x + v1.y * w0.y + v1.z * w0.z + v1.w * w0.w;
            aB1 += v1.x * w1.x + v1.y * w1.y + v1.z * w1.z + v1.w * w1.w;
            aA2 += v2.x * w0.x + v2.y * w0.y + v2.z * w0.z + v2.w * w0.w;
            aB2 += v2.x * w1.x + v2.y * w1.y + v2.z * w1.z + v2.w * w1.w;
            aA3 += v3.x * w0.x + v3.y * w0.y + v3.z * w0.z + v3.w * w0.w;
            aB3 += v3.x * w1.x + v3.y * w1.y + v3.z * w1.z + v3.w * w1.w;
        }

        // ---- (3) recurrent poll -> hrec[p] (slot (t-1)&3, tag t) ----
        {
            const ull* rr_ = ringOwn + ((t + 3) & 3) * 1024;
            const uint want = (uint)t;
            uint pend = 0x3u; ull v0, v1; int tries = 0;
            for (;;) {
                if (pend & 1u) v0 = aload64(&rr_[tid]);
                if (pend & 2u) v1 = aload64(&rr_[tid + 512]);
                if ((pend & 1u) && (uint)v0 == want) {
                    hrec[p][srow][scol] = __uint_as_float((uint)(v0 >> 32));
                    pend &= ~1u;
                }
                if ((pend & 2u) && (uint)v1 == want) {
                    hrec[p][srow + 2][scol] = __uint_as_float((uint)(v1 >> 32));
                    pend &= ~2u;
                }
                if (!pend) break;
                if (++tries > 4) __builtin_amdgcn_s_sleep(1);
            }
        }
        // ---- (4) WAR-gate verify (first read passes in steady state) ----
        if (tid < 16) {
            while (gv < t - 2) { __builtin_amdgcn_s_sleep(1); gv = aload(&mOwn[tid]); }
        } else if (layer == 0 && tid >= 32 && tid < 48) {
            while (gv < t - 3) { __builtin_amdgcn_s_sleep(1); gv = aload(&mSib[tid - 32]); }
        }
        __syncthreads();  // barrier 2: hrec[p] ready + gate passed
        if (tid == 0) astore(&mOwn[ug], t + 1);  // staged step t (inp + hrec in LDS)

        // ---- (5) h-part dot (K=256..511) ----
        #pragma unroll
        for (int j = 4; j < 8; ++j) {
            const int kof = (j - 4) * 64 + ks * 4;
            float4 w0 = wA[j], w1 = wB[j];
            float4 v0 = *(const float4*)&hrec[p][0][kof];
            float4 v1 = *(const float4*)&hrec[p][1][kof];
            float4 v2 = *(const float4*)&hrec[p][2][kof];
            float4 v3 = *(const float4*)&hrec[p][3][kof];
            aA0 += v0.x * w0.x + v0.y * w0.y + v0.z * w0.z + v0.w * w0.w;
            aB0 += v0.x * w1.x + v0.y * w1.y + v0.z * w1.z + v0.w * w1.w;
            aA1 += v1.x * w0.x + v1.y * w0.y + v1.z * w0.z + v1.w * w0.w;
            aB1 += v1.x * w1.x + v1.y * w1.y + v1.z * w1.z + v1.w * w1.w;
            aA2 += v2.x * w0.x + v2.y * w0.y + v2.z * w0.z + v2.w * w0.w;
            aB2 += v2.x * w1.x + v2.y * w1.y + v2.z * w1.z + v2.w * w1.w;
            aA3 += v3.x * w0.x + v3.y * w0.y + v3.z * w0.z + v3.w * w0.w;
            aB3 += v3.x * w1.x + v3.y * w1.y + v3.z * w1.z + v3.w * w1.w;
        }

        // ---- (6) butterfly over 16 ks lanes (xor 1,2,4,8) ----
        #pragma unroll
        for (int m = 1; m <= 8; m <<= 1) {
            aA0 += __shfl_xor(aA0, m);
            aA1 += __shfl_xor(aA1, m);
            aA2 += __shfl_xor(aA2, m);
            aA3 += __shfl_xor(aA3, m);
            aB0 += __shfl_xor(aB0, m);
            aB1 += __shfl_xor(aB1, m);
            aB2 += __shfl_xor(aB2, m);
            aB3 += __shfl_xor(aB3, m);
        }
        // ---- gate-pair exchange (xor 16): on gh==0 lanes these are o,chat sums ----
        float oA0 = __shfl_xor(aA0, 16), oA1 = __shfl_xor(aA1, 16);
        float oA2 = __shfl_xor(aA2, 16), oA3 = __shfl_xor(aA3, 16);
        float qB0 = __shfl_xor(aB0, 16), qB1 = __shfl_xor(aB1, 16);
        float qB2 = __shfl_xor(aB2, 16), qB3 = __shfl_xor(aB3, 16);

        // ---- (7) activations + publish (lanes gh==0 && ks<4: bl = ks) ----
        if (gh == 0 && ks < 4) {
            const int bl = ks;
            float iv = ks == 0 ? aA0 : ks == 1 ? aA1 : ks == 2 ? aA2 : aA3;
            float fv = ks == 0 ? aB0 : ks == 1 ? aB1 : ks == 2 ? aB2 : aB3;
            float ov = ks == 0 ? oA0 : ks == 1 ? oA1 : ks == 2 ? oA2 : oA3;
            float qv = ks == 0 ? qB0 : ks == 1 ? qB1 : ks == 2 ? qB2 : qB3;
            float ig = sigm(iv + bb[0]);
            float fg = sigm(fv + bb[1]);
            float og = sigm(ov + bb[2]);
            float ch = tanhf(qv + bb[3]);
            c_state = fg * c_state + ig * ch;
            float hn = og * tanhf(c_state);
            astore64(&ringOwn[(t & 3) * 1024 + bl * 256 + col],
                     ((ull)__float_as_uint(hn) << 32) | (ull)(uint)(t + 1));
            if (layer == 1) {
                const int bglob = grp * 4 + bl;
                out[((size_t)bglob * TT + t) * HH + col] = hn;
                if (t == TT - 1) {
                    float* tail = out + (size_t)BB * TT * HH;
                    tail[bglob * HH + col] = hn;                // hT (last layer)
                    tail[BB * HH + bglob * HH + col] = c_state; // cT (last layer)
                }
            }
        }
        // no end barrier: inp/hrec double-buffered; next step writes buffer p^1
    }
}

extern "C" void kernel_launch(void* const* d_in, const int* in_sizes, int n_in,
                              void* d_out, int out_size, void* d_ws, size_t ws_size,
                              hipStream_t stream) {
    (void)in_sizes; (void)n_in; (void)out_size; (void)ws_size;
    const float* x    = (const float*)d_in[0];
    const float* W    = (const float*)d_in[1];
    const float* bias = (const float*)d_in[2];
    float* out  = (float*)d_out;
    int*   sync = (int*)d_ws;
    ull*   ring = (ull*)((char*)d_ws + 4096);  // 16 communities x 32 KB = 512 KB

    hipMemsetAsync(d_ws, 0, 4096 + 16 * 4096 * sizeof(ull), stream);  // markers + tags
    hipLaunchKernelGGL(lstm_scan, dim3(256), dim3(NT), 0, stream, x, W, bias, out, ring, sync);
}